// Round 1
// baseline (184.528 us; speedup 1.0000x reference)
//
#include <hip/hip_runtime.h>

// H = relu(vfeat @ W + b), vfeat:[n,64], W:[64,64], b:[64]
__global__ __launch_bounds__(256) void lin_relu_kernel(
    const float* __restrict__ vfeat, const float* __restrict__ W,
    const float* __restrict__ b, float* __restrict__ H, int n_nodes)
{
    __shared__ float sW[64 * 64];
    __shared__ float sb[64];
    __shared__ float sv[4][64];

    const int tid = threadIdx.x;           // 256 threads
    for (int i = tid; i < 64 * 64; i += 256) sW[i] = W[i];
    if (tid < 64) sb[tid] = b[tid];
    __syncthreads();

    const int c    = tid & 63;             // output column (lane)
    const int rsub = tid >> 6;             // wave index 0..3 -> row within tile

    const int ntiles = (n_nodes + 3) >> 2;
    for (int tile = blockIdx.x; tile < ntiles; tile += gridDim.x) {
        const int r = tile * 4 + rsub;
        __syncthreads();                   // protect sv from previous iter readers
        if (r < n_nodes) sv[rsub][c] = vfeat[r * 64 + c];  // 256 contiguous floats
        __syncthreads();
        if (r < n_nodes) {
            float acc = sb[c];
            #pragma unroll
            for (int k = 0; k < 64; ++k)
                acc = fmaf(sv[rsub][k], sW[k * 64 + c], acc);  // sv broadcast, sW 2-way (free)
            H[r * 64 + c] = fmaxf(acc, 0.0f);
        }
    }
}

// out[2][E][64] : out[0][e] = H[src[e]], out[1][e] = H[dst[e]]
// One float4 per thread, 16 threads per row -> 1 KB contiguous store per wave.
__global__ __launch_bounds__(256) void gather_kernel(
    const float4* __restrict__ H, const int* __restrict__ src,
    const int* __restrict__ dst, float4* __restrict__ out, int E)
{
    const long total  = (long)2 * E * 16;
    const long stride = (long)gridDim.x * blockDim.x;
    for (long g = (long)blockIdx.x * blockDim.x + threadIdx.x; g < total; g += stride) {
        const long row = g >> 4;
        const int  c   = (int)(g & 15);
        int node;
        if (row < E) node = src[row];
        else         node = dst[row - E];
        out[g] = H[(long)node * 16 + c];
    }
}

extern "C" void kernel_launch(void* const* d_in, const int* in_sizes, int n_in,
                              void* d_out, int out_size, void* d_ws, size_t ws_size,
                              hipStream_t stream) {
    const float* vfeat = (const float*)d_in[0];
    const int*   src   = (const int*)d_in[1];
    const int*   dst   = (const int*)d_in[2];
    const float* W     = (const float*)d_in[3];
    const float* b     = (const float*)d_in[4];
    float* out = (float*)d_out;

    const int n_nodes = in_sizes[0] / 64;   // 50000
    const int E       = in_sizes[1];        // 1000000

    float* H = (float*)d_ws;                // n_nodes*64*4 = 12.8 MB

    // 1) H = relu(vfeat @ W + b)
    {
        int ntiles = (n_nodes + 3) >> 2;
        int grid = ntiles < 2048 ? ntiles : 2048;
        lin_relu_kernel<<<grid, 256, 0, stream>>>(vfeat, W, b, H, n_nodes);
    }

    // 2) gather into both output streams
    {
        int grid = 4096;
        gather_kernel<<<grid, 256, 0, stream>>>((const float4*)H, src, dst,
                                                (float4*)out, E);
    }
}

// Round 3
// 157.119 us; speedup vs baseline: 1.1744x; 1.1744x over previous
//
#include <hip/hip_runtime.h>

using fx4 = __attribute__((ext_vector_type(4))) float;

// H = relu(vfeat @ W + b), vfeat:[n,64], W:[64,64], b:[64]
// Each thread owns one output column c; W column held in 64 VGPRs.
// 8 rows staged in LDS per iteration; rows read back as broadcast ds_read_b128.
__global__ __launch_bounds__(256) void lin_relu_kernel(
    const float* __restrict__ vfeat, const float* __restrict__ W,
    const float* __restrict__ b, float* __restrict__ H, int n_nodes)
{
    __shared__ float sv[8][64];

    const int tid = threadIdx.x;     // 256
    const int c   = tid & 63;        // output column (lane)
    const int w   = tid >> 6;        // wave 0..3

    // W column c -> registers (coalesced: consecutive lanes read consecutive c)
    float wreg[64];
    #pragma unroll
    for (int k = 0; k < 64; ++k) wreg[k] = W[k * 64 + c];
    const float bc = b[c];

    const int ntiles = (n_nodes + 7) >> 3;
    for (int tile = blockIdx.x; tile < ntiles; tile += gridDim.x) {
        const int rbase = tile * 8;
        __syncthreads();             // protect sv from previous-iter readers
        // stage 8 rows (512 floats) with 256 threads -> 2 contiguous loads each
        {
            const int i0 = tid, i1 = tid + 256;
            const int r0 = rbase + (i0 >> 6);
            const int r1 = rbase + (i1 >> 6);
            if (r0 < n_nodes) sv[i0 >> 6][i0 & 63] = vfeat[r0 * 64 + (i0 & 63)];
            if (r1 < n_nodes) sv[i1 >> 6][i1 & 63] = vfeat[r1 * 64 + (i1 & 63)];
        }
        __syncthreads();
        // wave w computes rows rbase + 2w, rbase + 2w + 1
        #pragma unroll
        for (int rr = 0; rr < 2; ++rr) {
            const int rsub = w * 2 + rr;
            const int r    = rbase + rsub;
            if (r < n_nodes) {
                float acc = bc;
                const fx4* svp = (const fx4*)sv[rsub];   // broadcast ds_read_b128
                #pragma unroll
                for (int k4 = 0; k4 < 16; ++k4) {
                    const fx4 v = svp[k4];
                    acc = fmaf(v.x, wreg[k4 * 4 + 0], acc);
                    acc = fmaf(v.y, wreg[k4 * 4 + 1], acc);
                    acc = fmaf(v.z, wreg[k4 * 4 + 2], acc);
                    acc = fmaf(v.w, wreg[k4 * 4 + 3], acc);
                }
                H[r * 64 + c] = fmaxf(acc, 0.0f);
            }
        }
    }
}

// out[2][E][64] : out[0][e] = H[src[e]], out[1][e] = H[dst[e]]
// 16 threads per row, fx4 each -> 1 KB contiguous store per wave.
// Unroll x4 for 4 independent idx->H load chains; nontemporal stores keep
// H resident in L2/L3 instead of being evicted by the 512 MB output stream.
__global__ __launch_bounds__(256) void gather_kernel(
    const fx4* __restrict__ H, const int* __restrict__ src,
    const int* __restrict__ dst, fx4* __restrict__ out, int E)
{
    const long total  = (long)2 * E * 16;
    const long stride = (long)gridDim.x * blockDim.x;
    long g = (long)blockIdx.x * blockDim.x + threadIdx.x;

    for (; g + 3 * stride < total; g += 4 * stride) {
        int nd[4];
        #pragma unroll
        for (int u = 0; u < 4; ++u) {
            const long row = (g + u * stride) >> 4;
            const int* ip = (row < E) ? (src + row) : (dst + (row - E));
            nd[u] = *ip;
        }
        #pragma unroll
        for (int u = 0; u < 4; ++u) {
            const long gg = g + u * stride;
            const fx4 v = H[(long)nd[u] * 16 + (gg & 15)];
            __builtin_nontemporal_store(v, &out[gg]);
        }
    }
    for (; g < total; g += stride) {
        const long row = g >> 4;
        const int* ip = (row < E) ? (src + row) : (dst + (row - E));
        const fx4 v = H[(long)(*ip) * 16 + (g & 15)];
        __builtin_nontemporal_store(v, &out[g]);
    }
}

extern "C" void kernel_launch(void* const* d_in, const int* in_sizes, int n_in,
                              void* d_out, int out_size, void* d_ws, size_t ws_size,
                              hipStream_t stream) {
    const float* vfeat = (const float*)d_in[0];
    const int*   src   = (const int*)d_in[1];
    const int*   dst   = (const int*)d_in[2];
    const float* W     = (const float*)d_in[3];
    const float* b     = (const float*)d_in[4];
    float* out = (float*)d_out;

    const int n_nodes = in_sizes[0] / 64;   // 50000
    const int E       = in_sizes[1];        // 1000000

    float* H = (float*)d_ws;                // n_nodes*64*4 = 12.8 MB

    // 1) H = relu(vfeat @ W + b)
    {
        const int ntiles = (n_nodes + 7) >> 3;
        const int grid = ntiles < 2048 ? ntiles : 2048;
        lin_relu_kernel<<<grid, 256, 0, stream>>>(vfeat, W, b, H, n_nodes);
    }

    // 2) gather into both output streams
    gather_kernel<<<4096, 256, 0, stream>>>((const fx4*)H, src, dst,
                                            (fx4*)out, E);
}